// Round 5
// baseline (931.877 us; speedup 1.0000x reference)
//
#include <hip/hip_runtime.h>
#include <cmath>

// MuSeGNN on MI355X — round 5: conflict-free skip3.
// r4 profile: skip3 = 141us, SQ_LDS_BANK_CONFLICT = 1.43e7, VALUBusy 49%.
// Cause: rowb stride 132 -> af scalar reads 8-way bank-conflicted (4*132 mod
// 32 = 16), Bs float4 pairs 4-way. Fix: stride 133 (spacing 20 mod 32 -> 4
// distinct banks/wave), cols/rows split 4+4 at distance 64 (2-way = free),
// 128-row tiles with TM=8 x TN=8 (64 FMA per 4 LDS instrs -> VALU-bound).
//
// Algebra (verified r1-r4, absmax 0.0): alpha_e = u[dst]·h[src] (+softmax-
// invariant const; bk drops), u = h·(Wq_h Wk_h^T/√C) + bq·Wk_h^T/√C.
// out[dst] = mean_h((Σ_e a_e h[src])·Wv_h + bv_h) + h@Wskip + bskip; deg=0
// rows lose the attention term AND bv (empty segment sum).

#define NN    10000
#define NTOT  80000
#define EE    320000
#define CH    128

__device__ __forceinline__ float rl_f(float v, int lane) {
    return __uint_as_float(__builtin_amdgcn_readlane(__float_as_uint(v), lane));
}

// ---------------------------------------------------------------------------
// Precompute: Bcat (128x640 = [Pm | Wskip]), biascat (640 = [r | bskip]),
// Wcomb (512x128 = Wv/4 stacked (h,c)-major), bvbar, BN scale/bias.
// ---------------------------------------------------------------------------
__global__ __launch_bounds__(256) void precompute_kernel(
    const float* __restrict__ Wq, const float* __restrict__ bq,
    const float* __restrict__ Wk, const float* __restrict__ Wv,
    const float* __restrict__ bv, const float* __restrict__ Wskip,
    const float* __restrict__ bskip,
    const float* __restrict__ bn_gamma, const float* __restrict__ bn_beta,
    const float* __restrict__ bn_mean, const float* __restrict__ bn_var,
    float* __restrict__ Bcat, float* __restrict__ biascat,
    float* __restrict__ Wcomb, float* __restrict__ bvbar,
    float* __restrict__ bnS, float* __restrict__ bnB)
{
    const float inv_sqrtC = 0.08838834764831845f;  // 1/sqrt(128)
    int idx = blockIdx.x * 256 + threadIdx.x;
    if (idx < 65536) {            // Pm part: Bcat[c, o] o<512
        int c = idx >> 9;
        int o = idx & 511;
        int hbase = o & ~127;
        int j = o & 127;
        const float* wq = Wq + c * 512 + hbase;
        const float* wk = Wk + j * 512 + hbase;
        float s = 0.f;
        for (int cc = 0; cc < 128; cc++) s = fmaf(wq[cc], wk[cc], s);
        Bcat[c * 640 + o] = s * inv_sqrtC;
        return;
    }
    idx -= 65536;
    if (idx < 16384) {            // Wskip part: Bcat[c, 512+n]
        int c = idx >> 7, n = idx & 127;
        Bcat[c * 640 + 512 + n] = Wskip[c * 128 + n];
        return;
    }
    idx -= 16384;
    if (idx < 512) {              // biascat[0..511] = r
        int o = idx, hbase = o & ~127, j = o & 127;
        const float* wk = Wk + j * 512 + hbase;
        const float* bqp = bq + hbase;
        float s = 0.f;
        for (int cc = 0; cc < 128; cc++) s = fmaf(bqp[cc], wk[cc], s);
        biascat[o] = s * inv_sqrtC;
        return;
    }
    idx -= 512;
    if (idx < 128) {              // biascat[512..639] = bskip
        biascat[512 + idx] = bskip[idx];
        return;
    }
    idx -= 128;
    if (idx < 65536) {            // Wcomb[k, n], k=(h,c): Wv[c, h*128+n] / 4
        int k = idx >> 7;
        int n = idx & 127;
        int h = k >> 7, c = k & 127;
        Wcomb[k * 128 + n] = Wv[c * 512 + h * 128 + n] * 0.25f;
        return;
    }
    idx -= 65536;
    if (idx < 128) {              // bvbar = mean over heads of bv
        float s = 0.f;
        for (int h = 0; h < 4; h++) s += bv[h * 128 + idx];
        bvbar[idx] = 0.25f * s;
        return;
    }
    idx -= 128;
    if (idx < 384) {              // BN fold (eval): y = x*scale + bias
        float sc = bn_gamma[idx] / sqrtf(bn_var[idx] + 1e-5f);
        bnS[idx] = sc;
        bnB[idx] = bn_beta[idx] - bn_mean[idx] * sc;
        return;
    }
}

// ---------------------------------------------------------------------------
// CSR build by dst
// ---------------------------------------------------------------------------
__global__ void count_kernel(const int* __restrict__ dst, int* __restrict__ deg) {
    int e = blockIdx.x * 256 + threadIdx.x;
    if (e < EE) atomicAdd(&deg[dst[e]], 1);
}

__global__ __launch_bounds__(1024) void scan_kernel(const int* __restrict__ deg,
                                                    int* __restrict__ rowstart) {
    __shared__ int part[1024];
    const int t = threadIdx.x;
    int loc[10];
    int s = 0;
    for (int i = 0; i < 10; i++) {
        int idx = t * 10 + i;
        int v = (idx < NN) ? deg[idx] : 0;
        loc[i] = s; s += v;
    }
    part[t] = s; __syncthreads();
    for (int d = 1; d < 1024; d <<= 1) {
        int v = (t >= d) ? part[t - d] : 0;
        __syncthreads();
        part[t] += v;
        __syncthreads();
    }
    int base = (t == 0) ? 0 : part[t - 1];
    for (int i = 0; i < 10; i++) {
        int idx = t * 10 + i;
        if (idx <= NN) rowstart[idx] = base + loc[i];
    }
}

__global__ void scatter_kernel(const int* __restrict__ src, const int* __restrict__ dst,
                               const int* __restrict__ rowstart, int* __restrict__ cursor,
                               int* __restrict__ csr_src) {
    int e = blockIdx.x * 256 + threadIdx.x;
    if (e < EE) {
        int d = dst[e];
        int p = atomicAdd(&cursor[d], 1);
        csr_src[rowstart[d] + p] = src[e];
    }
}

// ---------------------------------------------------------------------------
// Upper rows (>= NN): 3-layer relu(bn(h@Wskip+bskip)) chain, 128-row tile
// LDS-resident across layers. Conflict-free geometry (see header comment).
// Sequential-k accumulation per output element == previous rounds (absmax 0).
// ---------------------------------------------------------------------------
#define S3 133   // rowb/Bs row stride: 4*133 % 32 = 20 -> af lanes hit 4 banks
__global__ __launch_bounds__(256) void skip3_kernel(
    const float* __restrict__ xup,    // Mup x 128
    const float* __restrict__ Wskip,  // 128 x 128
    const float* __restrict__ bskip,
    const float* __restrict__ bnS, const float* __restrict__ bnB,  // [3][128]
    float* __restrict__ h3up, int Mup)
{
    __shared__ float rowb[128 * S3];   // 68.1 KB
    __shared__ float Bs[16 * S3];      //  8.5 KB
    const int t  = threadIdx.x;
    const int tx = t & 15;             // col group
    const int ty = t >> 4;             // row group
    const int r0 = blockIdx.x * 128;
    const int Mrem = min(128, Mup - r0);
    const int ra = ty * 4;             // rows ra..ra+3 and 64+ra..64+ra+3
    const int ca = tx * 4;             // cols ca..ca+3 and 64+ca..64+ca+3

    // stage 128x128 input tile (row-major, float4)
    for (int f = t; f < 128 * 32; f += 256) {
        int row = f >> 5, c4 = (f & 31) * 4;
        if (row < Mrem)
            *(float4*)&rowb[row * S3 + c4] =
                *(const float4*)(xup + (size_t)(r0 + row) * CH + c4);
    }

    for (int l = 0; l < 3; l++) {
        float acc[8][8];
        #pragma unroll
        for (int i = 0; i < 8; i++)
            #pragma unroll
            for (int j = 0; j < 8; j++) acc[i][j] = 0.f;

        for (int k0 = 0; k0 < 128; k0 += 16) {
            __syncthreads();      // rowb/epilogue settled, Bs free
            for (int f = t; f < 16 * 32; f += 256) {
                int kk = f >> 5, n4 = (f & 31) * 4;
                *(float4*)&Bs[kk * S3 + n4] =
                    *(const float4*)(Wskip + (size_t)(k0 + kk) * 128 + n4);
            }
            __syncthreads();
            #pragma unroll
            for (int kk = 0; kk < 16; kk++) {
                const float4 b0 = *(const float4*)&Bs[kk * S3 + ca];
                const float4 b1 = *(const float4*)&Bs[kk * S3 + 64 + ca];
                const float bf[8] = {b0.x, b0.y, b0.z, b0.w, b1.x, b1.y, b1.z, b1.w};
                float af[8];
                #pragma unroll
                for (int i = 0; i < 4; i++) {
                    af[i]     = rowb[(ra + i) * S3 + k0 + kk];
                    af[4 + i] = rowb[(64 + ra + i) * S3 + k0 + kk];
                }
                #pragma unroll
                for (int i = 0; i < 8; i++)
                    #pragma unroll
                    for (int j = 0; j < 8; j++)
                        acc[i][j] = fmaf(af[i], bf[j], acc[i][j]);
            }
        }
        __syncthreads();          // all rowb reads of this layer done
        const float* bS = bnS + l * 128;
        const float* bB = bnB + l * 128;
        #pragma unroll
        for (int i = 0; i < 8; i++) {
            const int row = (i < 4) ? (ra + i) : (64 + ra + i - 4);
            #pragma unroll
            for (int jg = 0; jg < 2; jg++) {
                const int nb = jg * 64 + ca;
                float4 v;
                float* vp = &v.x;
                #pragma unroll
                for (int q = 0; q < 4; q++) {
                    const int n = nb + q;
                    float xv = acc[i][jg * 4 + q] + bskip[n];
                    xv = fmaf(xv, bS[n], bB[n]);
                    vp[q] = fmaxf(xv, 0.f);
                }
                *(float4*)&rowb[row * S3 + nb] = v;
            }
        }
        // next layer's leading __syncthreads() publishes rowb
    }
    __syncthreads();
    for (int f = t; f < 128 * 32; f += 256) {
        int row = f >> 5, c4 = (f & 31) * 4;
        if (row < Mrem)
            *(float4*)(h3up + (size_t)(r0 + row) * CH + c4) =
                *(const float4*)&rowb[row * S3 + c4];
    }
}

// ---------------------------------------------------------------------------
// fp32 tiled GEMM, 256 threads, BK=16.
// MODE 0 (ug): C = A*B + bias, dual dest: cols <512 -> C0 (u), >=512 -> C1
//              (raw lower skip; no BN).
// MODE 4 (comb'): C0 = relu(bn(A*B + Cold + (deg>0)*bias2))
// ---------------------------------------------------------------------------
template<int BM, int BN, int TM, int TN, int MODE>
__global__ __launch_bounds__(256) void gemm_fp32(
    const float* __restrict__ A, int lda,
    const float* __restrict__ B, int ldb,
    const float* __restrict__ bias, const float* __restrict__ bias2,
    const int* __restrict__ deg,
    const float* __restrict__ Cold,
    const float* __restrict__ bnS, const float* __restrict__ bnB,
    float* __restrict__ C0, int ldc0,
    float* __restrict__ C1, int ldc1,
    int M, int K)
{
    constexpr int BK = 16;
    __shared__ float As[BK][BM + 4];
    __shared__ float Bs[BK][BN + 4];
    const int t  = threadIdx.x;
    const int tx = t % (BN / TN);
    const int ty = t / (BN / TN);
    const int m0 = blockIdx.x * BM;
    const int n0 = blockIdx.y * BN;
    float acc[TM][TN];
    #pragma unroll
    for (int i = 0; i < TM; i++)
        #pragma unroll
        for (int j = 0; j < TN; j++) acc[i][j] = 0.f;

    for (int k0 = 0; k0 < K; k0 += BK) {
        #pragma unroll
        for (int f = t; f < BM * 4; f += 256) {
            int row = f >> 2, fc = f & 3;
            int gm = m0 + row;
            float4 v = make_float4(0.f, 0.f, 0.f, 0.f);
            if (gm < M) v = *(const float4*)(A + (size_t)gm * lda + k0 + fc * 4);
            As[fc * 4 + 0][row] = v.x;
            As[fc * 4 + 1][row] = v.y;
            As[fc * 4 + 2][row] = v.z;
            As[fc * 4 + 3][row] = v.w;
        }
        #pragma unroll
        for (int f = t; f < BK * (BN / 4); f += 256) {
            int kk = f / (BN / 4);
            int nn = (f % (BN / 4)) * 4;
            *(float4*)(&Bs[kk][nn]) = *(const float4*)(B + (size_t)(k0 + kk) * ldb + n0 + nn);
        }
        __syncthreads();
        #pragma unroll
        for (int kk = 0; kk < BK; kk++) {
            float af[TM], bf[TN];
            if constexpr (TM == 2) {
                float2 v = *(const float2*)&As[kk][ty * 2];
                af[0] = v.x; af[1] = v.y;
            } else {
                #pragma unroll
                for (int ii = 0; ii < TM; ii += 4) {
                    float4 v = *(const float4*)&As[kk][ty * TM + ii];
                    af[ii + 0] = v.x; af[ii + 1] = v.y; af[ii + 2] = v.z; af[ii + 3] = v.w;
                }
            }
            #pragma unroll
            for (int jj = 0; jj < TN; jj += 4) {
                float4 v = *(const float4*)&Bs[kk][tx * TN + jj];
                bf[jj + 0] = v.x; bf[jj + 1] = v.y; bf[jj + 2] = v.z; bf[jj + 3] = v.w;
            }
            #pragma unroll
            for (int i = 0; i < TM; i++)
                #pragma unroll
                for (int j = 0; j < TN; j++)
                    acc[i][j] = fmaf(af[i], bf[j], acc[i][j]);
        }
        __syncthreads();
    }
    // epilogue
    #pragma unroll
    for (int i = 0; i < TM; i++) {
        int gm = m0 + ty * TM + i;
        if (gm >= M) continue;
        const bool addB2 = (MODE == 4) ? (deg[gm] > 0) : false;
        #pragma unroll
        for (int j = 0; j < TN; j += 4) {
            const int nb = n0 + tx * TN + j;
            float4 v;
            float* vp = &v.x;
            if (MODE == 4) {
                const float4 old = *(const float4*)(Cold + (size_t)gm * ldc1 + nb);
                const float* op = &old.x;
                #pragma unroll
                for (int q = 0; q < 4; q++) {
                    const int n = nb + q;
                    float x = acc[i][j + q] + op[q];
                    if (addB2) x += bias2[n];
                    x = fmaf(x, bnS[n], bnB[n]);
                    vp[q] = fmaxf(x, 0.f);
                }
                *(float4*)(C0 + (size_t)gm * ldc0 + nb) = v;
            } else {
                #pragma unroll
                for (int q = 0; q < 4; q++)
                    vp[q] = acc[i][j + q] + bias[nb + q];
                if (nb < 512)
                    *(float4*)(C0 + (size_t)gm * ldc0 + nb) = v;
                else
                    *(float4*)(C1 + (size_t)gm * ldc1 + nb - 512) = v;
            }
        }
    }
}

// ---------------------------------------------------------------------------
// Attention: one block per dst node, chunked online softmax over CSR edges.
// ---------------------------------------------------------------------------
__global__ __launch_bounds__(256) void attn_kernel(
    const float* __restrict__ h,
    const float* __restrict__ u,
    float* __restrict__ g,
    const int* __restrict__ rowstart,
    const int* __restrict__ csr_src)
{
    __shared__ float h_lds[128 * 65];
    __shared__ __align__(16) float palpha[4 * 64 * 4];   // [ht][j][w]
    __shared__ __align__(16) float wT[64 * 4];           // [j][ht]
    __shared__ __align__(16) float scale_lds[4];
    __shared__ __align__(16) float s_lds[4];
    __shared__ __align__(16) float merge[128 * 4];
    __shared__ int src_lds[64];

    const int n  = blockIdx.x;
    const int t  = threadIdx.x;
    const int w  = t >> 6;      // wave id
    const int l  = t & 63;      // lane
    const int c  = t & 127;     // acc channel
    const int jh = t >> 7;      // acc j-half
    const int rs   = rowstart[n];
    const int degn = rowstart[n + 1] - rs;

    if (degn == 0) {
        g[(size_t)n * 512 + t] = 0.f;
        g[(size_t)n * 512 + 256 + t] = 0.f;
        return;
    }
    float u_reg0 = u[(size_t)n * 512 + ((l >> 5)) * 128 + 32 * w + (l & 31)];
    float u_reg1 = u[(size_t)n * 512 + ((l >> 5) + 2) * 128 + 32 * w + (l & 31)];

    float m_run = -INFINITY, s_run = 0.f;
    float4 acc4 = make_float4(0.f, 0.f, 0.f, 0.f);

    for (int base = 0; base < degn; base += 64) {
        const int len = min(64, degn - base);
        __syncthreads();
        if (t < len) src_lds[t] = csr_src[rs + base + t];
        __syncthreads();
        for (int f = t; f < len * 32; f += 256) {
            const int j = f >> 5, c4 = (f & 31) * 4;
            const float4 v = *(const float4*)(h + (size_t)src_lds[j] * CH + c4);
            h_lds[(c4 + 0) * 65 + j] = v.x;
            h_lds[(c4 + 1) * 65 + j] = v.y;
            h_lds[(c4 + 2) * 65 + j] = v.z;
            h_lds[(c4 + 3) * 65 + j] = v.w;
        }
        __syncthreads();
        {
            float p0 = 0.f, p1 = 0.f, p2 = 0.f, p3 = 0.f;
            #pragma unroll
            for (int dc = 0; dc < 32; dc++) {
                const float hv = h_lds[(32 * w + dc) * 65 + l];
                p0 = fmaf(rl_f(u_reg0, dc),      hv, p0);
                p1 = fmaf(rl_f(u_reg0, 32 + dc), hv, p1);
                p2 = fmaf(rl_f(u_reg1, dc),      hv, p2);
                p3 = fmaf(rl_f(u_reg1, 32 + dc), hv, p3);
            }
            palpha[(0 * 64 + l) * 4 + w] = p0;
            palpha[(1 * 64 + l) * 4 + w] = p1;
            palpha[(2 * 64 + l) * 4 + w] = p2;
            palpha[(3 * 64 + l) * 4 + w] = p3;
        }
        __syncthreads();
        {
            const float4 pa = *(const float4*)&palpha[(w * 64 + l) * 4];
            float alpha = (l < len) ? (pa.x + pa.y + pa.z + pa.w) : -INFINITY;
            float mx = alpha;
            #pragma unroll
            for (int d = 1; d < 64; d <<= 1) mx = fmaxf(mx, __shfl_xor(mx, d, 64));
            const float newm = fmaxf(m_run, mx);
            float e = (l < len) ? __expf(alpha - newm) : 0.f;
            float ss = e;
            #pragma unroll
            for (int d = 1; d < 64; d <<= 1) ss += __shfl_xor(ss, d, 64);
            const float sc = (m_run == -INFINITY) ? 0.f : __expf(m_run - newm);
            s_run = s_run * sc + ss;
            m_run = newm;
            wT[l * 4 + w] = e;
            if (l == 0) scale_lds[w] = sc;
        }
        __syncthreads();
        {
            const float4 scv = *(const float4*)scale_lds;
            acc4.x *= scv.x; acc4.y *= scv.y; acc4.z *= scv.z; acc4.w *= scv.w;
            const int j0 = jh * 32;
            const int j1 = min(len, j0 + 32);
            for (int j = j0; j < j1; j++) {
                const float hv = h_lds[c * 65 + j];
                const float4 wv = *(const float4*)&wT[j * 4];
                acc4.x = fmaf(wv.x, hv, acc4.x);
                acc4.y = fmaf(wv.y, hv, acc4.y);
                acc4.z = fmaf(wv.z, hv, acc4.z);
                acc4.w = fmaf(wv.w, hv, acc4.w);
            }
        }
    }
    if (l == 0) s_lds[w] = s_run;
    __syncthreads();
    if (jh == 1) *(float4*)&merge[c * 4] = acc4;
    __syncthreads();
    if (jh == 0) {
        const float4 o  = *(const float4*)&merge[c * 4];
        const float4 sv = *(const float4*)s_lds;
        g[(size_t)n * 512 + 0 * 128 + c] = (acc4.x + o.x) / (sv.x + 1e-16f);
        g[(size_t)n * 512 + 1 * 128 + c] = (acc4.y + o.y) / (sv.y + 1e-16f);
        g[(size_t)n * 512 + 2 * 128 + c] = (acc4.z + o.z) / (sv.z + 1e-16f);
        g[(size_t)n * 512 + 3 * 128 + c] = (acc4.w + o.w) / (sv.w + 1e-16f);
    }
}

// ---------------------------------------------------------------------------
// Radix-select sort-pool (exact, stable-tie; keys post-ReLU => uint-monotone)
// ---------------------------------------------------------------------------
__global__ __launch_bounds__(256) void radix_pool_kernel(
    const float* __restrict__ h3, const float* __restrict__ age,
    float* __restrict__ z)
{
    __shared__ unsigned int keys[NN];
    __shared__ int hist[256];
    __shared__ int sbuf[256];
    __shared__ unsigned int sel_prefix;
    __shared__ int sel_need;
    __shared__ int gt_counter;
    __shared__ unsigned int cand_key[30];
    __shared__ int cand_idx[30];
    __shared__ int order[30];

    const int b = blockIdx.x;
    const int t = threadIdx.x;

    for (int i = t; i < NN; i += 256)
        keys[i] = __float_as_uint(h3[((size_t)b * NN + i) * CH + 127]);
    if (t == 0) { sel_prefix = 0u; sel_need = 30; gt_counter = 0; }
    __syncthreads();

    for (int r = 3; r >= 0; r--) {
        hist[t] = 0;
        __syncthreads();
        const int shift = r * 8;
        const unsigned int pmask = (r == 3) ? 0u : (0xFFFFFFFFu << ((r + 1) * 8));
        const unsigned int pref = sel_prefix;
        const int need = sel_need;
        for (int i = t; i < NN; i += 256) {
            unsigned int k = keys[i];
            if ((k & pmask) == pref)
                atomicAdd(&hist[(k >> shift) & 255u], 1);
        }
        __syncthreads();
        sbuf[t] = hist[255 - t];
        __syncthreads();
        for (int d = 1; d < 256; d <<= 1) {
            int o = (t >= d) ? sbuf[t - d] : 0;
            __syncthreads();
            sbuf[t] += o;
            __syncthreads();
        }
        {
            const int v = t;
            const int ge = sbuf[255 - v];
            const int gt = ge - hist[v];
            if (gt < need && need <= ge) {
                sel_prefix = pref | ((unsigned int)v << shift);
                sel_need = need - gt;
            }
        }
        __syncthreads();
    }

    const unsigned int T = sel_prefix;
    const int need_eq = sel_need;
    const int n_gt = 30 - need_eq;

    for (int i = t; i < NN; i += 256) {
        unsigned int k = keys[i];
        if (k > T) {
            int p = atomicAdd(&gt_counter, 1);
            cand_key[p] = k; cand_idx[p] = i;
        }
    }
    {
        const int CHK = (NN + 255) / 256;
        const int i0 = t * CHK, i1 = min(NN, i0 + CHK);
        int local = 0;
        for (int i = i0; i < i1; i++) if (keys[i] == T) local++;
        sbuf[t] = local;
        __syncthreads();
        for (int d = 1; d < 256; d <<= 1) {
            int o = (t >= d) ? sbuf[t - d] : 0;
            __syncthreads();
            sbuf[t] += o;
            __syncthreads();
        }
        int rank = (t == 0) ? 0 : sbuf[t - 1];
        for (int i = i0; i < i1; i++) {
            if (keys[i] == T) {
                if (rank < need_eq) { cand_key[n_gt + rank] = T; cand_idx[n_gt + rank] = i; }
                rank++;
            }
        }
    }
    __syncthreads();
    if (t < 30) {
        const unsigned int mk = cand_key[t];
        const int mi = cand_idx[t];
        int rk = 0;
        for (int j = 0; j < 30; j++) {
            const unsigned int ok = cand_key[j];
            const int oi = cand_idx[j];
            if (ok > mk || (ok == mk && oi < mi)) rk++;
        }
        order[rk] = t;
    }
    __syncthreads();
    for (int f = t; f < 30 * CH; f += 256) {
        int kk = f >> 7, cc = f & 127;
        z[(size_t)b * 3841 + f] = h3[((size_t)b * NN + cand_idx[order[kk]]) * CH + cc];
    }
    if (t == 0) z[(size_t)b * 3841 + 3840] = age[b];
}

// ---------------------------------------------------------------------------
// MLP head
// ---------------------------------------------------------------------------
__global__ __launch_bounds__(256) void mlp1_kernel(
    const float* __restrict__ z, const float* __restrict__ W1,
    float* __restrict__ zh)
{
    __shared__ float zs[256];
    const int b  = blockIdx.x >> 4;
    const int ic = blockIdx.x & 15;
    const int t  = threadIdx.x;
    const int i0 = ic * 241;
    const int i1 = min(3841, i0 + 241);
    float a0 = 0.f, a1 = 0.f;
    for (int cb = i0; cb < i1; cb += 256) {
        int cl = min(256, i1 - cb);
        __syncthreads();
        if (t < cl) zs[t] = z[(size_t)b * 3841 + cb + t];
        __syncthreads();
        #pragma unroll 4
        for (int q = 0; q < cl; q++) {
            float zv = zs[q];
            const float* wp = W1 + (size_t)(cb + q) * 512;
            a0 = fmaf(zv, wp[t], a0);
            a1 = fmaf(zv, wp[t + 256], a1);
        }
    }
    atomicAdd(&zh[(size_t)b * 512 + t], a0);
    atomicAdd(&zh[(size_t)b * 512 + t + 256], a1);
}

__global__ __launch_bounds__(256) void mlp2_kernel(
    const float* __restrict__ zh, const float* __restrict__ b1,
    const float* __restrict__ W2, const float* __restrict__ b2,
    float* __restrict__ out)
{
    __shared__ float r0[256], r1[256];
    const int b = blockIdx.x;
    const int t = threadIdx.x;
    float a0 = 0.f, a1 = 0.f;
    for (int j = t; j < 512; j += 256) {
        float v = fmaxf(zh[(size_t)b * 512 + j] + b1[j], 0.f);
        a0 = fmaf(v, W2[j * 2 + 0], a0);
        a1 = fmaf(v, W2[j * 2 + 1], a1);
    }
    r0[t] = a0; r1[t] = a1; __syncthreads();
    for (int s = 128; s > 0; s >>= 1) {
        if (t < s) { r0[t] += r0[t + s]; r1[t] += r1[t + s]; }
        __syncthreads();
    }
    if (t == 0) {
        float l0 = r0[0] + b2[0], l1 = r1[0] + b2[1];
        float m = fmaxf(l0, l1);
        float lse = m + logf(__expf(l0 - m) + __expf(l1 - m));
        out[b * 2 + 0] = l0 - lse;
        out[b * 2 + 1] = l1 - lse;
    }
}

// ---------------------------------------------------------------------------
extern "C" void kernel_launch(void* const* d_in, const int* in_sizes, int n_in,
                              void* d_out, int out_size, void* d_ws, size_t ws_size,
                              hipStream_t stream) {
    const float* x     = (const float*)d_in[0];
    const int*   ei    = (const int*)d_in[1];
    const float* age   = (const float*)d_in[2];
    const float* Wq    = (const float*)d_in[3];
    const float* bq    = (const float*)d_in[4];
    const float* Wk    = (const float*)d_in[5];
    // d_in[6] = bk: provably softmax-invariant, unused.
    const float* Wv    = (const float*)d_in[7];
    const float* bv    = (const float*)d_in[8];
    const float* Wskip = (const float*)d_in[9];
    const float* bskip = (const float*)d_in[10];
    const float* bn_g  = (const float*)d_in[11];
    const float* bn_b  = (const float*)d_in[12];
    const float* bn_m  = (const float*)d_in[13];
    const float* bn_v  = (const float*)d_in[14];
    const float* W1    = (const float*)d_in[15];
    const float* b1    = (const float*)d_in[16];
    const float* W2    = (const float*)d_in[17];
    const float* b2    = (const float*)d_in[18];

    float* ws = (float*)d_ws;
    float* h3      = ws;                     // 10,240,000 (80000x128)
    float* hlowA   = h3 + 10240000;          // 1,280,000
    float* hlowB   = hlowA + 1280000;        // 1,280,000
    float* u       = hlowB + 1280000;        // 5,120,000 (g aliases u)
    float* skipraw = u + 5120000;            // 1,280,000
    float* Bcat    = skipraw + 1280000;      // 81,920
    float* biascat = Bcat + 81920;           // 640
    float* Wcomb   = biascat + 640;          // 65,536
    float* bvbar   = Wcomb + 65536;          // 128
    float* bnS     = bvbar + 128;            // 384
    float* bnB     = bnS + 384;              // 384
    float* zbuf    = bnB + 384;              // 30,728
    float* zh      = zbuf + 30728;           // 4,096
    int* deg      = (int*)(zh + 4096);       // 10,000
    int* cursor   = deg + NN;                // 10,000
    int* rowstart = cursor + NN;             // 10,001
    int* csr_src  = rowstart + NN + 1;       // 320,000

    const int* srcI = ei;
    const int* dstI = ei + EE;

    hipMemsetAsync(deg, 0, sizeof(int) * (2 * NN), stream);   // deg + cursor
    hipMemsetAsync(zh, 0, sizeof(float) * 4096, stream);

    precompute_kernel<<<581, 256, 0, stream>>>(Wq, bq, Wk, Wv, bv, Wskip, bskip,
                                               bn_g, bn_b, bn_m, bn_v,
                                               Bcat, biascat, Wcomb, bvbar, bnS, bnB);
    count_kernel<<<1250, 256, 0, stream>>>(dstI, deg);
    scan_kernel<<<1, 1024, 0, stream>>>(deg, rowstart);
    scatter_kernel<<<1250, 256, 0, stream>>>(srcI, dstI, rowstart, cursor, csr_src);

    // upper 70000 rows: all 3 layers fused, 128-row tiles, writes h3[NN:]
    skip3_kernel<<<547, 256, 0, stream>>>(x + (size_t)NN * CH, Wskip, bskip,
                                          bnS, bnB, h3 + (size_t)NN * CH,
                                          NTOT - NN);

    const float* hcur = x;                   // lower-row slice (rows 0..NN-1)
    for (int l = 0; l < 3; l++) {
        float* dest = (l == 0) ? hlowA : (l == 1) ? hlowB : h3;  // h3 rows 0..NN-1
        // [u | raw skip] = h_low @ [Pm | Wskip] + [r | bskip]   (1570 blocks)
        gemm_fp32<64, 64, 4, 4, 0><<<dim3(157, 10), 256, 0, stream>>>(
            hcur, CH, Bcat, 640, biascat, nullptr, nullptr, nullptr,
            nullptr, nullptr, u, 512, skipraw, CH, NN, 128);
        // g = softmax-weighted neighbor sums of h, aliased onto u
        attn_kernel<<<NN, 256, 0, stream>>>(hcur, u, u, rowstart, csr_src);
        // h_next = relu(bn(g @ Wvstack + skipraw + (deg>0)*bvbar))  (626 blocks)
        gemm_fp32<32, 64, 2, 4, 4><<<dim3(313, 2), 256, 0, stream>>>(
            u, 512, Wcomb, CH, nullptr, bvbar, deg, skipraw,
            bnS + l * 128, bnB + l * 128, dest, CH, nullptr, CH, NN, 512);
        hcur = dest;
    }
    radix_pool_kernel<<<8, 256, 0, stream>>>(h3, age, zbuf);
    mlp1_kernel<<<128, 256, 0, stream>>>(zbuf, W1, zh);
    mlp2_kernel<<<8, 256, 0, stream>>>(zh, b1, W2, b2, (float*)d_out);
}

// Round 6
// 883.109 us; speedup vs baseline: 1.0552x; 1.0552x over previous
//
#include <hip/hip_runtime.h>
#include <cmath>

// MuSeGNN on MI355X — round 6: skip3 = r4 occupancy + r5 bank geometry.
// r5 post-mortem: 128-row tile (76.6KB LDS) -> 2 blocks/CU, 8 waves, VALU 29%
// -> 234us (worse than r4's 141). r4's conflicts were the Bs reads (tx*8
// spacing -> 4-way bank-quad aliasing), NOT the af reads (2-way = free).
// This round: 64-row tiles (41.6KB -> 3 blocks/CU, 1094 blocks), stride 130
// (af row spacing 4*130 % 32 = 8 -> 4 distinct banks, 16-lane broadcast),
// cols split tx*4 / 64+tx*4 (2-way = free). Plus BK=32 GEMMs (half the
// barriers in ug/comb).
//
// Algebra (verified r1-r5, absmax 0.0): alpha_e = u[dst]·h[src] (+softmax-
// invariant const; bk drops), u = h·(Wq_h Wk_h^T/√C) + bq·Wk_h^T/√C.
// out[dst] = mean_h((Σ_e a_e h[src])·Wv_h + bv_h) + h@Wskip + bskip; deg=0
// rows lose the attention term AND bv (empty segment sum).

#define NN    10000
#define NTOT  80000
#define EE    320000
#define CH    128

__device__ __forceinline__ float rl_f(float v, int lane) {
    return __uint_as_float(__builtin_amdgcn_readlane(__float_as_uint(v), lane));
}

// ---------------------------------------------------------------------------
// Precompute: Bcat (128x640 = [Pm | Wskip]), biascat (640 = [r | bskip]),
// Wcomb (512x128 = Wv/4 stacked (h,c)-major), bvbar, BN scale/bias.
// ---------------------------------------------------------------------------
__global__ __launch_bounds__(256) void precompute_kernel(
    const float* __restrict__ Wq, const float* __restrict__ bq,
    const float* __restrict__ Wk, const float* __restrict__ Wv,
    const float* __restrict__ bv, const float* __restrict__ Wskip,
    const float* __restrict__ bskip,
    const float* __restrict__ bn_gamma, const float* __restrict__ bn_beta,
    const float* __restrict__ bn_mean, const float* __restrict__ bn_var,
    float* __restrict__ Bcat, float* __restrict__ biascat,
    float* __restrict__ Wcomb, float* __restrict__ bvbar,
    float* __restrict__ bnS, float* __restrict__ bnB)
{
    const float inv_sqrtC = 0.08838834764831845f;  // 1/sqrt(128)
    int idx = blockIdx.x * 256 + threadIdx.x;
    if (idx < 65536) {            // Pm part: Bcat[c, o] o<512
        int c = idx >> 9;
        int o = idx & 511;
        int hbase = o & ~127;
        int j = o & 127;
        const float* wq = Wq + c * 512 + hbase;
        const float* wk = Wk + j * 512 + hbase;
        float s = 0.f;
        for (int cc = 0; cc < 128; cc++) s = fmaf(wq[cc], wk[cc], s);
        Bcat[c * 640 + o] = s * inv_sqrtC;
        return;
    }
    idx -= 65536;
    if (idx < 16384) {            // Wskip part: Bcat[c, 512+n]
        int c = idx >> 7, n = idx & 127;
        Bcat[c * 640 + 512 + n] = Wskip[c * 128 + n];
        return;
    }
    idx -= 16384;
    if (idx < 512) {              // biascat[0..511] = r
        int o = idx, hbase = o & ~127, j = o & 127;
        const float* wk = Wk + j * 512 + hbase;
        const float* bqp = bq + hbase;
        float s = 0.f;
        for (int cc = 0; cc < 128; cc++) s = fmaf(bqp[cc], wk[cc], s);
        biascat[o] = s * inv_sqrtC;
        return;
    }
    idx -= 512;
    if (idx < 128) {              // biascat[512..639] = bskip
        biascat[512 + idx] = bskip[idx];
        return;
    }
    idx -= 128;
    if (idx < 65536) {            // Wcomb[k, n], k=(h,c): Wv[c, h*128+n] / 4
        int k = idx >> 7;
        int n = idx & 127;
        int h = k >> 7, c = k & 127;
        Wcomb[k * 128 + n] = Wv[c * 512 + h * 128 + n] * 0.25f;
        return;
    }
    idx -= 65536;
    if (idx < 128) {              // bvbar = mean over heads of bv
        float s = 0.f;
        for (int h = 0; h < 4; h++) s += bv[h * 128 + idx];
        bvbar[idx] = 0.25f * s;
        return;
    }
    idx -= 128;
    if (idx < 384) {              // BN fold (eval): y = x*scale + bias
        float sc = bn_gamma[idx] / sqrtf(bn_var[idx] + 1e-5f);
        bnS[idx] = sc;
        bnB[idx] = bn_beta[idx] - bn_mean[idx] * sc;
        return;
    }
}

// ---------------------------------------------------------------------------
// CSR build by dst
// ---------------------------------------------------------------------------
__global__ void count_kernel(const int* __restrict__ dst, int* __restrict__ deg) {
    int e = blockIdx.x * 256 + threadIdx.x;
    if (e < EE) atomicAdd(&deg[dst[e]], 1);
}

__global__ __launch_bounds__(1024) void scan_kernel(const int* __restrict__ deg,
                                                    int* __restrict__ rowstart) {
    __shared__ int part[1024];
    const int t = threadIdx.x;
    int loc[10];
    int s = 0;
    for (int i = 0; i < 10; i++) {
        int idx = t * 10 + i;
        int v = (idx < NN) ? deg[idx] : 0;
        loc[i] = s; s += v;
    }
    part[t] = s; __syncthreads();
    for (int d = 1; d < 1024; d <<= 1) {
        int v = (t >= d) ? part[t - d] : 0;
        __syncthreads();
        part[t] += v;
        __syncthreads();
    }
    int base = (t == 0) ? 0 : part[t - 1];
    for (int i = 0; i < 10; i++) {
        int idx = t * 10 + i;
        if (idx <= NN) rowstart[idx] = base + loc[i];
    }
}

__global__ void scatter_kernel(const int* __restrict__ src, const int* __restrict__ dst,
                               const int* __restrict__ rowstart, int* __restrict__ cursor,
                               int* __restrict__ csr_src) {
    int e = blockIdx.x * 256 + threadIdx.x;
    if (e < EE) {
        int d = dst[e];
        int p = atomicAdd(&cursor[d], 1);
        csr_src[rowstart[d] + p] = src[e];
    }
}

// ---------------------------------------------------------------------------
// Upper rows (>= NN): 3-layer relu(bn(h@Wskip+bskip)) chain, 64-row tile
// LDS-resident across layers. Stride 130: af rows at 4*130%32=8 -> banks
// {0,8,16,24} (conflict-free, 16-lane broadcast); bf cols tx*4 & 64+tx*4
// -> 2-way (free). 41.6KB LDS -> 3 blocks/CU. Sequential-k accumulation
// per output element == reference association (absmax 0).
// ---------------------------------------------------------------------------
#define S3 130
__global__ __launch_bounds__(256) void skip3_kernel(
    const float* __restrict__ xup,    // Mup x 128
    const float* __restrict__ Wskip,  // 128 x 128
    const float* __restrict__ bskip,
    const float* __restrict__ bnS, const float* __restrict__ bnB,  // [3][128]
    float* __restrict__ h3up, int Mup)
{
    __shared__ float rowb[64 * S3];    // 33.3 KB
    __shared__ float Bs[16 * S3];      //  8.3 KB
    const int t  = threadIdx.x;
    const int tx = t & 15;             // col group
    const int ty = t >> 4;             // row group
    const int r0 = blockIdx.x * 64;
    const int Mrem = min(64, Mup - r0);
    const int ra = ty * 4;             // rows ra..ra+3
    const int ca = tx * 4;             // cols ca..ca+3 and 64+ca..64+ca+3

    // stage 64x128 input tile (row-major, float4)
    for (int f = t; f < 64 * 32; f += 256) {
        int row = f >> 5, c4 = (f & 31) * 4;
        if (row < Mrem)
            *(float4*)&rowb[row * S3 + c4] =
                *(const float4*)(xup + (size_t)(r0 + row) * CH + c4);
    }

    for (int l = 0; l < 3; l++) {
        float acc[4][8];
        #pragma unroll
        for (int i = 0; i < 4; i++)
            #pragma unroll
            for (int j = 0; j < 8; j++) acc[i][j] = 0.f;

        for (int k0 = 0; k0 < 128; k0 += 16) {
            __syncthreads();      // rowb/epilogue settled, Bs free
            for (int f = t; f < 16 * 32; f += 256) {
                int kk = f >> 5, n4 = (f & 31) * 4;
                *(float4*)&Bs[kk * S3 + n4] =
                    *(const float4*)(Wskip + (size_t)(k0 + kk) * 128 + n4);
            }
            __syncthreads();
            #pragma unroll
            for (int kk = 0; kk < 16; kk++) {
                const float4 b0 = *(const float4*)&Bs[kk * S3 + ca];
                const float4 b1 = *(const float4*)&Bs[kk * S3 + 64 + ca];
                const float bf[8] = {b0.x, b0.y, b0.z, b0.w, b1.x, b1.y, b1.z, b1.w};
                #pragma unroll
                for (int i = 0; i < 4; i++) {
                    const float af = rowb[(ra + i) * S3 + k0 + kk];
                    #pragma unroll
                    for (int j = 0; j < 8; j++)
                        acc[i][j] = fmaf(af, bf[j], acc[i][j]);
                }
            }
        }
        __syncthreads();          // all rowb reads of this layer done
        const float* bS = bnS + l * 128;
        const float* bB = bnB + l * 128;
        #pragma unroll
        for (int i = 0; i < 4; i++) {
            #pragma unroll
            for (int jg = 0; jg < 2; jg++) {
                const int nb = jg * 64 + ca;
                float4 v;
                float* vp = &v.x;
                #pragma unroll
                for (int q = 0; q < 4; q++) {
                    const int n = nb + q;
                    float xv = acc[i][jg * 4 + q] + bskip[n];
                    xv = fmaf(xv, bS[n], bB[n]);
                    vp[q] = fmaxf(xv, 0.f);
                }
                *(float4*)&rowb[(ra + i) * S3 + nb] = v;
            }
        }
        // next layer's leading __syncthreads() publishes rowb
    }
    __syncthreads();
    for (int f = t; f < 64 * 32; f += 256) {
        int row = f >> 5, c4 = (f & 31) * 4;
        if (row < Mrem)
            *(float4*)(h3up + (size_t)(r0 + row) * CH + c4) =
                *(const float4*)&rowb[row * S3 + c4];
    }
}

// ---------------------------------------------------------------------------
// fp32 tiled GEMM, 256 threads, templated BK.
// MODE 0 (ug): C = A*B + bias, dual dest: cols <512 -> C0 (u), >=512 -> C1
//              (raw lower skip; no BN).
// MODE 4 (comb'): C0 = relu(bn(A*B + Cold + (deg>0)*bias2))
// ---------------------------------------------------------------------------
template<int BM, int BN, int BK, int TM, int TN, int MODE>
__global__ __launch_bounds__(256) void gemm_fp32(
    const float* __restrict__ A, int lda,
    const float* __restrict__ B, int ldb,
    const float* __restrict__ bias, const float* __restrict__ bias2,
    const int* __restrict__ deg,
    const float* __restrict__ Cold,
    const float* __restrict__ bnS, const float* __restrict__ bnB,
    float* __restrict__ C0, int ldc0,
    float* __restrict__ C1, int ldc1,
    int M, int K)
{
    constexpr int BKC = BK / 4;
    __shared__ float As[BK][BM + 4];
    __shared__ float Bs[BK][BN + 4];
    const int t  = threadIdx.x;
    const int tx = t % (BN / TN);
    const int ty = t / (BN / TN);
    const int m0 = blockIdx.x * BM;
    const int n0 = blockIdx.y * BN;
    float acc[TM][TN];
    #pragma unroll
    for (int i = 0; i < TM; i++)
        #pragma unroll
        for (int j = 0; j < TN; j++) acc[i][j] = 0.f;

    for (int k0 = 0; k0 < K; k0 += BK) {
        #pragma unroll
        for (int f = t; f < BM * BKC; f += 256) {
            int row = f / BKC, fc = f % BKC;
            int gm = m0 + row;
            float4 v = make_float4(0.f, 0.f, 0.f, 0.f);
            if (gm < M) v = *(const float4*)(A + (size_t)gm * lda + k0 + fc * 4);
            As[fc * 4 + 0][row] = v.x;
            As[fc * 4 + 1][row] = v.y;
            As[fc * 4 + 2][row] = v.z;
            As[fc * 4 + 3][row] = v.w;
        }
        #pragma unroll
        for (int f = t; f < BK * (BN / 4); f += 256) {
            int kk = f / (BN / 4);
            int nn = (f % (BN / 4)) * 4;
            *(float4*)(&Bs[kk][nn]) = *(const float4*)(B + (size_t)(k0 + kk) * ldb + n0 + nn);
        }
        __syncthreads();
        #pragma unroll
        for (int kk = 0; kk < BK; kk++) {
            float af[TM], bf[TN];
            if constexpr (TM == 2) {
                float2 v = *(const float2*)&As[kk][ty * 2];
                af[0] = v.x; af[1] = v.y;
            } else {
                #pragma unroll
                for (int ii = 0; ii < TM; ii += 4) {
                    float4 v = *(const float4*)&As[kk][ty * TM + ii];
                    af[ii + 0] = v.x; af[ii + 1] = v.y; af[ii + 2] = v.z; af[ii + 3] = v.w;
                }
            }
            #pragma unroll
            for (int jj = 0; jj < TN; jj += 4) {
                float4 v = *(const float4*)&Bs[kk][tx * TN + jj];
                bf[jj + 0] = v.x; bf[jj + 1] = v.y; bf[jj + 2] = v.z; bf[jj + 3] = v.w;
            }
            #pragma unroll
            for (int i = 0; i < TM; i++)
                #pragma unroll
                for (int j = 0; j < TN; j++)
                    acc[i][j] = fmaf(af[i], bf[j], acc[i][j]);
        }
        __syncthreads();
    }
    // epilogue
    #pragma unroll
    for (int i = 0; i < TM; i++) {
        int gm = m0 + ty * TM + i;
        if (gm >= M) continue;
        const bool addB2 = (MODE == 4) ? (deg[gm] > 0) : false;
        #pragma unroll
        for (int j = 0; j < TN; j += 4) {
            const int nb = n0 + tx * TN + j;
            float4 v;
            float* vp = &v.x;
            if (MODE == 4) {
                const float4 old = *(const float4*)(Cold + (size_t)gm * ldc1 + nb);
                const float* op = &old.x;
                #pragma unroll
                for (int q = 0; q < 4; q++) {
                    const int n = nb + q;
                    float x = acc[i][j + q] + op[q];
                    if (addB2) x += bias2[n];
                    x = fmaf(x, bnS[n], bnB[n]);
                    vp[q] = fmaxf(x, 0.f);
                }
                *(float4*)(C0 + (size_t)gm * ldc0 + nb) = v;
            } else {
                #pragma unroll
                for (int q = 0; q < 4; q++)
                    vp[q] = acc[i][j + q] + bias[nb + q];
                if (nb < 512)
                    *(float4*)(C0 + (size_t)gm * ldc0 + nb) = v;
                else
                    *(float4*)(C1 + (size_t)gm * ldc1 + nb - 512) = v;
            }
        }
    }
}

// ---------------------------------------------------------------------------
// Attention: one block per dst node, chunked online softmax over CSR edges.
// ---------------------------------------------------------------------------
__global__ __launch_bounds__(256) void attn_kernel(
    const float* __restrict__ h,
    const float* __restrict__ u,
    float* __restrict__ g,
    const int* __restrict__ rowstart,
    const int* __restrict__ csr_src)
{
    __shared__ float h_lds[128 * 65];
    __shared__ __align__(16) float palpha[4 * 64 * 4];   // [ht][j][w]
    __shared__ __align__(16) float wT[64 * 4];           // [j][ht]
    __shared__ __align__(16) float scale_lds[4];
    __shared__ __align__(16) float s_lds[4];
    __shared__ __align__(16) float merge[128 * 4];
    __shared__ int src_lds[64];

    const int n  = blockIdx.x;
    const int t  = threadIdx.x;
    const int w  = t >> 6;      // wave id
    const int l  = t & 63;      // lane
    const int c  = t & 127;     // acc channel
    const int jh = t >> 7;      // acc j-half
    const int rs   = rowstart[n];
    const int degn = rowstart[n + 1] - rs;

    if (degn == 0) {
        g[(size_t)n * 512 + t] = 0.f;
        g[(size_t)n * 512 + 256 + t] = 0.f;
        return;
    }
    float u_reg0 = u[(size_t)n * 512 + ((l >> 5)) * 128 + 32 * w + (l & 31)];
    float u_reg1 = u[(size_t)n * 512 + ((l >> 5) + 2) * 128 + 32 * w + (l & 31)];

    float m_run = -INFINITY, s_run = 0.f;
    float4 acc4 = make_float4(0.f, 0.f, 0.f, 0.f);

    for (int base = 0; base < degn; base += 64) {
        const int len = min(64, degn - base);
        __syncthreads();
        if (t < len) src_lds[t] = csr_src[rs + base + t];
        __syncthreads();
        for (int f = t; f < len * 32; f += 256) {
            const int j = f >> 5, c4 = (f & 31) * 4;
            const float4 v = *(const float4*)(h + (size_t)src_lds[j] * CH + c4);
            h_lds[(c4 + 0) * 65 + j] = v.x;
            h_lds[(c4 + 1) * 65 + j] = v.y;
            h_lds[(c4 + 2) * 65 + j] = v.z;
            h_lds[(c4 + 3) * 65 + j] = v.w;
        }
        __syncthreads();
        {
            float p0 = 0.f, p1 = 0.f, p2 = 0.f, p3 = 0.f;
            #pragma unroll
            for (int dc = 0; dc < 32; dc++) {
                const float hv = h_lds[(32 * w + dc) * 65 + l];
                p0 = fmaf(rl_f(u_reg0, dc),      hv, p0);
                p1 = fmaf(rl_f(u_reg0, 32 + dc), hv, p1);
                p2 = fmaf(rl_f(u_reg1, dc),      hv, p2);
                p3 = fmaf(rl_f(u_reg1, 32 + dc), hv, p3);
            }
            palpha[(0 * 64 + l) * 4 + w] = p0;
            palpha[(1 * 64 + l) * 4 + w] = p1;
            palpha[(2 * 64 + l) * 4 + w] = p2;
            palpha[(3 * 64 + l) * 4 + w] = p3;
        }
        __syncthreads();
        {
            const float4 pa = *(const float4*)&palpha[(w * 64 + l) * 4];
            float alpha = (l < len) ? (pa.x + pa.y + pa.z + pa.w) : -INFINITY;
            float mx = alpha;
            #pragma unroll
            for (int d = 1; d < 64; d <<= 1) mx = fmaxf(mx, __shfl_xor(mx, d, 64));
            const float newm = fmaxf(m_run, mx);
            float e = (l < len) ? __expf(alpha - newm) : 0.f;
            float ss = e;
            #pragma unroll
            for (int d = 1; d < 64; d <<= 1) ss += __shfl_xor(ss, d, 64);
            const float sc = (m_run == -INFINITY) ? 0.f : __expf(m_run - newm);
            s_run = s_run * sc + ss;
            m_run = newm;
            wT[l * 4 + w] = e;
            if (l == 0) scale_lds[w] = sc;
        }
        __syncthreads();
        {
            const float4 scv = *(const float4*)scale_lds;
            acc4.x *= scv.x; acc4.y *= scv.y; acc4.z *= scv.z; acc4.w *= scv.w;
            const int j0 = jh * 32;
            const int j1 = min(len, j0 + 32);
            for (int j = j0; j < j1; j++) {
                const float hv = h_lds[c * 65 + j];
                const float4 wv = *(const float4*)&wT[j * 4];
                acc4.x = fmaf(wv.x, hv, acc4.x);
                acc4.y = fmaf(wv.y, hv, acc4.y);
                acc4.z = fmaf(wv.z, hv, acc4.z);
                acc4.w = fmaf(wv.w, hv, acc4.w);
            }
        }
    }
    if (l == 0) s_lds[w] = s_run;
    __syncthreads();
    if (jh == 1) *(float4*)&merge[c * 4] = acc4;
    __syncthreads();
    if (jh == 0) {
        const float4 o  = *(const float4*)&merge[c * 4];
        const float4 sv = *(const float4*)s_lds;
        g[(size_t)n * 512 + 0 * 128 + c] = (acc4.x + o.x) / (sv.x + 1e-16f);
        g[(size_t)n * 512 + 1 * 128 + c] = (acc4.y + o.y) / (sv.y + 1e-16f);
        g[(size_t)n * 512 + 2 * 128 + c] = (acc4.z + o.z) / (sv.z + 1e-16f);
        g[(size_t)n * 512 + 3 * 128 + c] = (acc4.w + o.w) / (sv.w + 1e-16f);
    }
}

// ---------------------------------------------------------------------------
// Radix-select sort-pool (exact, stable-tie; keys post-ReLU => uint-monotone)
// ---------------------------------------------------------------------------
__global__ __launch_bounds__(256) void radix_pool_kernel(
    const float* __restrict__ h3, const float* __restrict__ age,
    float* __restrict__ z)
{
    __shared__ unsigned int keys[NN];
    __shared__ int hist[256];
    __shared__ int sbuf[256];
    __shared__ unsigned int sel_prefix;
    __shared__ int sel_need;
    __shared__ int gt_counter;
    __shared__ unsigned int cand_key[30];
    __shared__ int cand_idx[30];
    __shared__ int order[30];

    const int b = blockIdx.x;
    const int t = threadIdx.x;

    for (int i = t; i < NN; i += 256)
        keys[i] = __float_as_uint(h3[((size_t)b * NN + i) * CH + 127]);
    if (t == 0) { sel_prefix = 0u; sel_need = 30; gt_counter = 0; }
    __syncthreads();

    for (int r = 3; r >= 0; r--) {
        hist[t] = 0;
        __syncthreads();
        const int shift = r * 8;
        const unsigned int pmask = (r == 3) ? 0u : (0xFFFFFFFFu << ((r + 1) * 8));
        const unsigned int pref = sel_prefix;
        const int need = sel_need;
        for (int i = t; i < NN; i += 256) {
            unsigned int k = keys[i];
            if ((k & pmask) == pref)
                atomicAdd(&hist[(k >> shift) & 255u], 1);
        }
        __syncthreads();
        sbuf[t] = hist[255 - t];
        __syncthreads();
        for (int d = 1; d < 256; d <<= 1) {
            int o = (t >= d) ? sbuf[t - d] : 0;
            __syncthreads();
            sbuf[t] += o;
            __syncthreads();
        }
        {
            const int v = t;
            const int ge = sbuf[255 - v];
            const int gt = ge - hist[v];
            if (gt < need && need <= ge) {
                sel_prefix = pref | ((unsigned int)v << shift);
                sel_need = need - gt;
            }
        }
        __syncthreads();
    }

    const unsigned int T = sel_prefix;
    const int need_eq = sel_need;
    const int n_gt = 30 - need_eq;

    for (int i = t; i < NN; i += 256) {
        unsigned int k = keys[i];
        if (k > T) {
            int p = atomicAdd(&gt_counter, 1);
            cand_key[p] = k; cand_idx[p] = i;
        }
    }
    {
        const int CHK = (NN + 255) / 256;
        const int i0 = t * CHK, i1 = min(NN, i0 + CHK);
        int local = 0;
        for (int i = i0; i < i1; i++) if (keys[i] == T) local++;
        sbuf[t] = local;
        __syncthreads();
        for (int d = 1; d < 256; d <<= 1) {
            int o = (t >= d) ? sbuf[t - d] : 0;
            __syncthreads();
            sbuf[t] += o;
            __syncthreads();
        }
        int rank = (t == 0) ? 0 : sbuf[t - 1];
        for (int i = i0; i < i1; i++) {
            if (keys[i] == T) {
                if (rank < need_eq) { cand_key[n_gt + rank] = T; cand_idx[n_gt + rank] = i; }
                rank++;
            }
        }
    }
    __syncthreads();
    if (t < 30) {
        const unsigned int mk = cand_key[t];
        const int mi = cand_idx[t];
        int rk = 0;
        for (int j = 0; j < 30; j++) {
            const unsigned int ok = cand_key[j];
            const int oi = cand_idx[j];
            if (ok > mk || (ok == mk && oi < mi)) rk++;
        }
        order[rk] = t;
    }
    __syncthreads();
    for (int f = t; f < 30 * CH; f += 256) {
        int kk = f >> 7, cc = f & 127;
        z[(size_t)b * 3841 + f] = h3[((size_t)b * NN + cand_idx[order[kk]]) * CH + cc];
    }
    if (t == 0) z[(size_t)b * 3841 + 3840] = age[b];
}

// ---------------------------------------------------------------------------
// MLP head
// ---------------------------------------------------------------------------
__global__ __launch_bounds__(256) void mlp1_kernel(
    const float* __restrict__ z, const float* __restrict__ W1,
    float* __restrict__ zh)
{
    __shared__ float zs[256];
    const int b  = blockIdx.x >> 4;
    const int ic = blockIdx.x & 15;
    const int t  = threadIdx.x;
    const int i0 = ic * 241;
    const int i1 = min(3841, i0 + 241);
    float a0 = 0.f, a1 = 0.f;
    for (int cb = i0; cb < i1; cb += 256) {
        int cl = min(256, i1 - cb);
        __syncthreads();
        if (t < cl) zs[t] = z[(size_t)b * 3841 + cb + t];
        __syncthreads();
        #pragma unroll 4
        for (int q = 0; q < cl; q++) {
            float zv = zs[q];
            const float* wp = W1 + (size_t)(cb + q) * 512;
            a0 = fmaf(zv, wp[t], a0);
            a1 = fmaf(zv, wp[t + 256], a1);
        }
    }
    atomicAdd(&zh[(size_t)b * 512 + t], a0);
    atomicAdd(&zh[(size_t)b * 512 + t + 256], a1);
}

__global__ __launch_bounds__(256) void mlp2_kernel(
    const float* __restrict__ zh, const float* __restrict__ b1,
    const float* __restrict__ W2, const float* __restrict__ b2,
    float* __restrict__ out)
{
    __shared__ float r0[256], r1[256];
    const int b = blockIdx.x;
    const int t = threadIdx.x;
    float a0 = 0.f, a1 = 0.f;
    for (int j = t; j < 512; j += 256) {
        float v = fmaxf(zh[(size_t)b * 512 + j] + b1[j], 0.f);
        a0 = fmaf(v, W2[j * 2 + 0], a0);
        a1 = fmaf(v, W2[j * 2 + 1], a1);
    }
    r0[t] = a0; r1[t] = a1; __syncthreads();
    for (int s = 128; s > 0; s >>= 1) {
        if (t < s) { r0[t] += r0[t + s]; r1[t] += r1[t + s]; }
        __syncthreads();
    }
    if (t == 0) {
        float l0 = r0[0] + b2[0], l1 = r1[0] + b2[1];
        float m = fmaxf(l0, l1);
        float lse = m + logf(__expf(l0 - m) + __expf(l1 - m));
        out[b * 2 + 0] = l0 - lse;
        out[b * 2 + 1] = l1 - lse;
    }
}

// ---------------------------------------------------------------------------
extern "C" void kernel_launch(void* const* d_in, const int* in_sizes, int n_in,
                              void* d_out, int out_size, void* d_ws, size_t ws_size,
                              hipStream_t stream) {
    const float* x     = (const float*)d_in[0];
    const int*   ei    = (const int*)d_in[1];
    const float* age   = (const float*)d_in[2];
    const float* Wq    = (const float*)d_in[3];
    const float* bq    = (const float*)d_in[4];
    const float* Wk    = (const float*)d_in[5];
    // d_in[6] = bk: provably softmax-invariant, unused.
    const float* Wv    = (const float*)d_in[7];
    const float* bv    = (const float*)d_in[8];
    const float* Wskip = (const float*)d_in[9];
    const float* bskip = (const float*)d_in[10];
    const float* bn_g  = (const float*)d_in[11];
    const float* bn_b  = (const float*)d_in[12];
    const float* bn_m  = (const float*)d_in[13];
    const float* bn_v  = (const float*)d_in[14];
    const float* W1    = (const float*)d_in[15];
    const float* b1    = (const float*)d_in[16];
    const float* W2    = (const float*)d_in[17];
    const float* b2    = (const float*)d_in[18];

    float* ws = (float*)d_ws;
    float* h3      = ws;                     // 10,240,000 (80000x128)
    float* hlowA   = h3 + 10240000;          // 1,280,000
    float* hlowB   = hlowA + 1280000;        // 1,280,000
    float* u       = hlowB + 1280000;        // 5,120,000 (g aliases u)
    float* skipraw = u + 5120000;            // 1,280,000
    float* Bcat    = skipraw + 1280000;      // 81,920
    float* biascat = Bcat + 81920;           // 640
    float* Wcomb   = biascat + 640;          // 65,536
    float* bvbar   = Wcomb + 65536;          // 128
    float* bnS     = bvbar + 128;            // 384
    float* bnB     = bnS + 384;              // 384
    float* zbuf    = bnB + 384;              // 30,728
    float* zh      = zbuf + 30728;           // 4,096
    int* deg      = (int*)(zh + 4096);       // 10,000
    int* cursor   = deg + NN;                // 10,000
    int* rowstart = cursor + NN;             // 10,001
    int* csr_src  = rowstart + NN + 1;       // 320,000

    const int* srcI = ei;
    const int* dstI = ei + EE;

    hipMemsetAsync(deg, 0, sizeof(int) * (2 * NN), stream);   // deg + cursor
    hipMemsetAsync(zh, 0, sizeof(float) * 4096, stream);

    precompute_kernel<<<581, 256, 0, stream>>>(Wq, bq, Wk, Wv, bv, Wskip, bskip,
                                               bn_g, bn_b, bn_m, bn_v,
                                               Bcat, biascat, Wcomb, bvbar, bnS, bnB);
    count_kernel<<<1250, 256, 0, stream>>>(dstI, deg);
    scan_kernel<<<1, 1024, 0, stream>>>(deg, rowstart);
    scatter_kernel<<<1250, 256, 0, stream>>>(srcI, dstI, rowstart, cursor, csr_src);

    // upper 70000 rows: all 3 layers fused, 64-row tiles, writes h3[NN:]
    skip3_kernel<<<1094, 256, 0, stream>>>(x + (size_t)NN * CH, Wskip, bskip,
                                           bnS, bnB, h3 + (size_t)NN * CH,
                                           NTOT - NN);

    const float* hcur = x;                   // lower-row slice (rows 0..NN-1)
    for (int l = 0; l < 3; l++) {
        float* dest = (l == 0) ? hlowA : (l == 1) ? hlowB : h3;  // h3 rows 0..NN-1
        // [u | raw skip] = h_low @ [Pm | Wskip] + [r | bskip]   (1570 blocks)
        gemm_fp32<64, 64, 32, 4, 4, 0><<<dim3(157, 10), 256, 0, stream>>>(
            hcur, CH, Bcat, 640, biascat, nullptr, nullptr, nullptr,
            nullptr, nullptr, u, 512, skipraw, CH, NN, 128);
        // g = softmax-weighted neighbor sums of h, aliased onto u
        attn_kernel<<<NN, 256, 0, stream>>>(hcur, u, u, rowstart, csr_src);
        // h_next = relu(bn(g @ Wvstack + skipraw + (deg>0)*bvbar))  (626 blocks)
        gemm_fp32<32, 64, 32, 2, 4, 4><<<dim3(313, 2), 256, 0, stream>>>(
            u, 512, Wcomb, CH, nullptr, bvbar, deg, skipraw,
            bnS + l * 128, bnB + l * 128, dest, CH, nullptr, CH, NN, 512);
        hcur = dest;
    }
    radix_pool_kernel<<<8, 256, 0, stream>>>(h3, age, zbuf);
    mlp1_kernel<<<128, 256, 0, stream>>>(zbuf, W1, zh);
    mlp2_kernel<<<8, 256, 0, stream>>>(zh, b1, W2, b2, (float*)d_out);
}